// Round 8
// baseline (36386.435 us; speedup 1.0000x reference)
//
#include <hip/hip_runtime.h>
#include <hip/hip_bf16.h>
#include <math.h>

// Problem constants (fixed by the reference)
#define T_STEPS 4096
#define N_IN    8192
#define N_OUT   2048

// ---------------------------------------------------------------------------
// Kernel 1: u_proj = x @ Win   (f32 vector GEMM, 128x128 tile, BK=16)
//   Writes into d_out; the recurrence consumes/overwrites it in place.
// ---------------------------------------------------------------------------
#define GM_BK 16

__global__ __launch_bounds__(256) void gemm_xwin(const float* __restrict__ X,
                                                 const float* __restrict__ Win,
                                                 float* __restrict__ U) {
    const int K = N_IN, N = N_OUT;
    __shared__ float As[GM_BK][128 + 4];
    __shared__ float Bs[GM_BK][128 + 4];

    const int tid = threadIdx.x;
    const int bm = blockIdx.x;
    const int bn = blockIdx.y;
    const int tx = tid & 15;
    const int ty = tid >> 4;

    float acc[8][8];
#pragma unroll
    for (int i = 0; i < 8; i++)
#pragma unroll
        for (int j = 0; j < 8; j++) acc[i][j] = 0.f;

    const float* Xb = X + (size_t)(bm * 128) * K;
    const float* Wb = Win + bn * 128;

    for (int kt = 0; kt < K; kt += GM_BK) {
#pragma unroll
        for (int q = 0; q < 2; q++) {
            const int r  = (tid >> 2) + q * 64;
            const int c4 = (tid & 3) * 4;
            const float4 a4 = *reinterpret_cast<const float4*>(&Xb[(size_t)r * K + kt + c4]);
            As[c4 + 0][r] = a4.x;
            As[c4 + 1][r] = a4.y;
            As[c4 + 2][r] = a4.z;
            As[c4 + 3][r] = a4.w;
        }
#pragma unroll
        for (int q = 0; q < 2; q++) {
            const int r  = (tid >> 5) + q * 8;
            const int c4 = (tid & 31) * 4;
            *reinterpret_cast<float4*>(&Bs[r][c4]) =
                *reinterpret_cast<const float4*>(&Wb[(size_t)(kt + r) * N + c4]);
        }
        __syncthreads();

#pragma unroll
        for (int k = 0; k < GM_BK; k++) {
            float a[8], b[8];
#pragma unroll
            for (int i = 0; i < 4; i++) {
                a[i]     = As[k][ty * 4 + i];
                a[4 + i] = As[k][64 + ty * 4 + i];
            }
#pragma unroll
            for (int j = 0; j < 4; j++) {
                b[j]     = Bs[k][tx * 4 + j];
                b[4 + j] = Bs[k][64 + tx * 4 + j];
            }
#pragma unroll
            for (int i = 0; i < 8; i++)
#pragma unroll
                for (int j = 0; j < 8; j++)
                    acc[i][j] = fmaf(a[i], b[j], acc[i][j]);
        }
        __syncthreads();
    }

#pragma unroll
    for (int i = 0; i < 8; i++) {
        const int mr = bm * 128 + ((i < 4) ? (ty * 4 + i) : (64 + ty * 4 + (i - 4)));
        float* Crow = U + (size_t)mr * N + bn * 128;
        float4 v0 = make_float4(acc[i][0], acc[i][1], acc[i][2], acc[i][3]);
        float4 v1 = make_float4(acc[i][4], acc[i][5], acc[i][6], acc[i][7]);
        *reinterpret_cast<float4*>(&Crow[tx * 4])      = v0;
        *reinterpret_cast<float4*>(&Crow[64 + tx * 4]) = v1;
    }
}

// ---------------------------------------------------------------------------
// Kernel 2: ESN recurrence v8 = XCD-LOCAL tagged-slot exchange.
//   32 blocks x 256 threads, ALL on XCD 0 (self-selected via HW_REG_XCC_ID +
//   device-scope ticket; blocks elsewhere exit). All state exchange uses sc0
//   loads/stores -> coherent through XCD0's shared L2 (~200ns) instead of the
//   LLC (~500-700ns). Producers dual-store {tag,val} slots: primary (sc0,L2)
//   + mirror (agent scope, LLC). Consumers poll primary; after 6 failed
//   rounds they poll the mirror -> correct even if the sc0-L2 assumption is
//   wrong (degrades to ~r5 speed instead of hanging).
//   Output is deterministic: columns are assigned by ticket (0..31), so any
//   physical block assignment computes identical values in identical order.
//   Rotation safety (4-deep, t&3): storing tag t+1 implies having read ALL of
//   v_t => every block stored v_t => ... => all reads of v_{t-3} completed.
//   vsh double-buffered (t&1) + single barrier: a thread can be at most one
//   step ahead of a same-block peer (the barrier separates them).
// ---------------------------------------------------------------------------
#define NPART 32          // participating blocks (one XCD)
#define CPB   64          // columns per block
#define GRP   4           // lanes per column
#define CAP   288         // nnz capacity per column (mean 204.8, sigma 13.6)
#define KMAX  (CAP / GRP) // 72 register entries per lane
#define SCN   16          // columns per setup chunk

__device__ __forceinline__ float fast_tanh(float x) {
    const float ax = fabsf(x);
    const float e  = __expf(2.0f * ax);               // inf for big ax
    const float r  = __builtin_amdgcn_rcpf(e + 1.0f); // rcp(inf)=0 -> tanh=1
    const float t  = 1.0f - 2.0f * r;
    return copysignf(t, x);
}

__device__ __forceinline__ unsigned xcc_id() {
    unsigned x;
    asm("s_getreg_b32 %0, hwreg(HW_REG_XCC_ID)" : "=s"(x));
    return x;
}

// one batched round: 8 sc0 loads (L1-bypass, served by this XCD's L2) + wait
#define POLL8(pp)                                                        \
    asm volatile(                                                        \
        "global_load_dwordx2 %0, %8, off sc0\n\t"                        \
        "global_load_dwordx2 %1, %8, off offset:8 sc0\n\t"               \
        "global_load_dwordx2 %2, %8, off offset:16 sc0\n\t"              \
        "global_load_dwordx2 %3, %8, off offset:24 sc0\n\t"              \
        "global_load_dwordx2 %4, %8, off offset:32 sc0\n\t"              \
        "global_load_dwordx2 %5, %8, off offset:40 sc0\n\t"              \
        "global_load_dwordx2 %6, %8, off offset:48 sc0\n\t"              \
        "global_load_dwordx2 %7, %8, off offset:56 sc0\n\t"              \
        "s_waitcnt vmcnt(0)"                                             \
        : "=&v"(q0), "=&v"(q1), "=&v"(q2), "=&v"(q3),                    \
          "=&v"(q4), "=&v"(q5), "=&v"(q6), "=&v"(q7)                     \
        : "v"(pp)                                                        \
        : "memory")

#define CHK(i, qi)                                                       \
    if (pend & (1u << i)) {                                              \
        if ((unsigned)((qi) >> 32) == ut)                                \
            dst[base + i] = __uint_as_float((unsigned)(qi));             \
        else                                                             \
            np |= (1u << i);                                             \
    }

#define MIRR(i, qi)                                                      \
    if (pend & (1u << i))                                                \
        qi = __hip_atomic_load(&vmir[base + i], __ATOMIC_RELAXED,        \
                               __HIP_MEMORY_SCOPE_AGENT);

__global__ __launch_bounds__(256, 1) void esn_recur(const float* __restrict__ W,
                                                    float* __restrict__ UO,
                                                    unsigned long long* vprim,
                                                    unsigned long long* vmirror,
                                                    int* ticket) {
    __shared__ unsigned long long ent[SCN][CAP];  // setup scratch (chunked)
    __shared__ int   cnts[SCN];
    __shared__ float vsh[2][N_OUT];
    __shared__ int   tk_sh;

    if (xcc_id() != 0) return;                 // uniform across the block
    if (threadIdx.x == 0) tk_sh = atomicAdd(ticket, 1);
    __syncthreads();
    const int b = tk_sh;
    if (b >= NPART) return;

    const int tid = threadIdx.x;
    const int c   = tid >> 2;                  // column-in-block 0..63
    const int l   = tid & 3;                   // lane within column
    const int j   = b * CPB + c;               // global output column
    const int wave = tid >> 6;                 // == chunk of this thread's col

    // ---------- setup: 4 chunks of 16 columns (scan 16 lanes/col) ----------
    float wreg[KMAX];
    int   ireg[KMAX];
#pragma unroll 1
    for (int chunk = 0; chunk < 4; ++chunk) {
        const int jc = b * CPB + chunk * SCN + (tid >> 4);
        const int sl = tid & 15;
        int cnt = 0;
        for (int k = 0; k < N_OUT / 16; ++k)
            cnt += (W[(size_t)(sl + 16 * k) * N_OUT + jc] != 0.f) ? 1 : 0;
        int inc = cnt;
#pragma unroll
        for (int d = 1; d < 16; d <<= 1) {
            int n = __shfl_up(inc, d, 64);
            if (sl >= d) inc += n;
        }
        int pos = inc - cnt;
        if (sl == 15) cnts[tid >> 4] = inc;
        for (int k = 0; k < N_OUT / 16; ++k) {
            const int i = sl + 16 * k;
            const float w = W[(size_t)i * N_OUT + jc];
            if (w != 0.f) {
                if (pos < CAP)
                    ent[tid >> 4][pos] =
                        ((unsigned long long)(unsigned)i << 32) | __float_as_uint(w);
                pos++;
            }
        }
        __syncthreads();
        if (wave == chunk) {                   // wave-uniform condition
            const int cc   = c & 15;
            const int ccnt = min(cnts[cc], CAP);
#pragma unroll
            for (int k = 0; k < KMAX; ++k) {
                const int p = l + k * GRP;
                if (p < ccnt) {
                    const unsigned long long e = ent[cc][p];
                    wreg[k] = __uint_as_float((unsigned)e);
                    ireg[k] = (int)(e >> 32);
                } else {
                    wreg[k] = 0.f;             // pad: gathers vsh[0], w=0
                    ireg[k] = 0;
                }
            }
        }
        __syncthreads();
    }

    float vold  = 0.f;                         // carried leak-term state
    float u_cur = 0.f;                         // software-pipelined u load
    if (l == 0) u_cur = UO[j];

    // ---------- sequential scan over T ----------
#pragma unroll 1
    for (int t = 0; t < T_STEPS; ++t) {
        unsigned long long* vin = vprim + (size_t)(t & 3) * N_OUT;
        const unsigned long long* vmir = vmirror + (size_t)(t & 3) * N_OUT;
        float* dst = vsh[t & 1];
        const int base = tid * 8;              // this thread's 8 slots (64B line)
        const unsigned ut = (unsigned)t;

        unsigned long long q0, q1, q2, q3, q4, q5, q6, q7;
        const unsigned long long* pp = vin + base;
        POLL8(pp);
        unsigned pend = 0xFFu;
        int rounds = 0;
#pragma unroll 1
        while (true) {
            unsigned np = 0;
            CHK(0, q0) CHK(1, q1) CHK(2, q2) CHK(3, q3)
            CHK(4, q4) CHK(5, q5) CHK(6, q6) CHK(7, q7)
            pend = np;
            if (!pend) break;
            if (++rounds < 6) {
                POLL8(pp);                     // fast path: XCD-L2 round (~200ns)
            } else {
                MIRR(0, q0) MIRR(1, q1) MIRR(2, q2) MIRR(3, q3)
                MIRR(4, q4) MIRR(5, q5) MIRR(6, q6) MIRR(7, q7)
            }
        }
        __syncthreads();                       // vsh[t&1] complete

        // prefetch NEXT step's u (keeps HBM miss out of the poll's vmcnt)
        float u_nxt = 0.f;
        if (l == 0 && t + 1 < T_STEPS) u_nxt = UO[(size_t)(t + 1) * N_OUT + j];

        // ---- MAC from registers: 72 LDS gathers, 4 accumulators ----
        const float* vcur = vsh[t & 1];
        float y0 = 0.f, y1 = 0.f, y2 = 0.f, y3 = 0.f;
#pragma unroll
        for (int k = 0; k < KMAX; k += 4) {
            y0 = fmaf(wreg[k + 0], vcur[ireg[k + 0]], y0);
            y1 = fmaf(wreg[k + 1], vcur[ireg[k + 1]], y1);
            y2 = fmaf(wreg[k + 2], vcur[ireg[k + 2]], y2);
            y3 = fmaf(wreg[k + 3], vcur[ireg[k + 3]], y3);
        }
        float y = (y0 + y1) + (y2 + y3);
        y += __shfl_xor(y, 2, 64);
        y += __shfl_xor(y, 1, 64);

        if (l == 0) {
            const float vnew = 0.5f * vold + 0.5f * fast_tanh(y + u_cur);
            vold = vnew;
            const unsigned long long slot =
                ((unsigned long long)(unsigned)(t + 1) << 32) | __float_as_uint(vnew);
            // primary store first (XCD-L2 critical path), then LLC mirror, then UO
            unsigned long long* pd = vprim + (size_t)((t + 1) & 3) * N_OUT + j;
            asm volatile("global_store_dwordx2 %0, %1, off sc0"
                         :: "v"(pd), "v"(slot) : "memory");
            __hip_atomic_store(&vmirror[(size_t)((t + 1) & 3) * N_OUT + j], slot,
                               __ATOMIC_RELAXED, __HIP_MEMORY_SCOPE_AGENT);
            UO[(size_t)t * N_OUT + j] = vnew;  // block owns full 64B lines
        }
        u_cur = u_nxt;
    }
}

// ---------------------------------------------------------------------------
extern "C" void kernel_launch(void* const* d_in, const int* in_sizes, int n_in,
                              void* d_out, int out_size, void* d_ws, size_t ws_size,
                              hipStream_t stream) {
    const float* x   = (const float*)d_in[0];   // [4096, 8192]
    const float* W   = (const float*)d_in[1];   // [2048, 2048]
    const float* Win = (const float*)d_in[2];   // [8192, 2048]
    float* out = (float*)d_out;                 // [4096, 2048]

    unsigned long long* vprim   = (unsigned long long*)d_ws;             // 4x2048 u64
    unsigned long long* vmirror = vprim + 4 * N_OUT;                     // 4x2048 u64
    int* ticket = (int*)((char*)d_ws + 8 * N_OUT * sizeof(unsigned long long));

    // zero slots (tag0 = step-0 zero state), mirror, and the ticket counter
    hipMemsetAsync(d_ws, 0, 8 * N_OUT * sizeof(unsigned long long) + 64, stream);

    dim3 ggrid(T_STEPS / 128, N_OUT / 128);
    gemm_xwin<<<ggrid, 256, 0, stream>>>(x, Win, out);

    esn_recur<<<1024, 256, 0, stream>>>(W, out, vprim, vmirror, ticket);
}

// Round 9
// 11997.890 us; speedup vs baseline: 3.0327x; 3.0327x over previous
//
#include <hip/hip_runtime.h>
#include <hip/hip_bf16.h>
#include <math.h>

// Problem constants (fixed by the reference)
#define T_STEPS 4096
#define N_IN    8192
#define N_OUT   2048

// ---------------------------------------------------------------------------
// Kernel 1: u_proj = x @ Win   (f32 vector GEMM, 128x128 tile, BK=16)
//   Writes into d_out; the recurrence consumes/overwrites it in place.
// ---------------------------------------------------------------------------
#define GM_BK 16

__global__ __launch_bounds__(256) void gemm_xwin(const float* __restrict__ X,
                                                 const float* __restrict__ Win,
                                                 float* __restrict__ U) {
    const int K = N_IN, N = N_OUT;
    __shared__ float As[GM_BK][128 + 4];
    __shared__ float Bs[GM_BK][128 + 4];

    const int tid = threadIdx.x;
    const int bm = blockIdx.x;
    const int bn = blockIdx.y;
    const int tx = tid & 15;
    const int ty = tid >> 4;

    float acc[8][8];
#pragma unroll
    for (int i = 0; i < 8; i++)
#pragma unroll
        for (int j = 0; j < 8; j++) acc[i][j] = 0.f;

    const float* Xb = X + (size_t)(bm * 128) * K;
    const float* Wb = Win + bn * 128;

    for (int kt = 0; kt < K; kt += GM_BK) {
#pragma unroll
        for (int q = 0; q < 2; q++) {
            const int r  = (tid >> 2) + q * 64;
            const int c4 = (tid & 3) * 4;
            const float4 a4 = *reinterpret_cast<const float4*>(&Xb[(size_t)r * K + kt + c4]);
            As[c4 + 0][r] = a4.x;
            As[c4 + 1][r] = a4.y;
            As[c4 + 2][r] = a4.z;
            As[c4 + 3][r] = a4.w;
        }
#pragma unroll
        for (int q = 0; q < 2; q++) {
            const int r  = (tid >> 5) + q * 8;
            const int c4 = (tid & 31) * 4;
            *reinterpret_cast<float4*>(&Bs[r][c4]) =
                *reinterpret_cast<const float4*>(&Wb[(size_t)(kt + r) * N + c4]);
        }
        __syncthreads();

#pragma unroll
        for (int k = 0; k < GM_BK; k++) {
            float a[8], b[8];
#pragma unroll
            for (int i = 0; i < 4; i++) {
                a[i]     = As[k][ty * 4 + i];
                a[4 + i] = As[k][64 + ty * 4 + i];
            }
#pragma unroll
            for (int j = 0; j < 4; j++) {
                b[j]     = Bs[k][tx * 4 + j];
                b[4 + j] = Bs[k][64 + tx * 4 + j];
            }
#pragma unroll
            for (int i = 0; i < 8; i++)
#pragma unroll
                for (int j = 0; j < 8; j++)
                    acc[i][j] = fmaf(a[i], b[j], acc[i][j]);
        }
        __syncthreads();
    }

#pragma unroll
    for (int i = 0; i < 8; i++) {
        const int mr = bm * 128 + ((i < 4) ? (ty * 4 + i) : (64 + ty * 4 + (i - 4)));
        float* Crow = U + (size_t)mr * N + bn * 128;
        float4 v0 = make_float4(acc[i][0], acc[i][1], acc[i][2], acc[i][3]);
        float4 v1 = make_float4(acc[i][4], acc[i][5], acc[i][6], acc[i][7]);
        *reinterpret_cast<float4*>(&Crow[tx * 4])      = v0;
        *reinterpret_cast<float4*>(&Crow[64 + tx * 4]) = v1;
    }
}

// ---------------------------------------------------------------------------
// Kernel 2: sequential ESN recurrence, v9 = r5 structure + BANK-ROTATION SORT.
//   r5 (best: 2.84us/step): 64 blocks x 256 thr, 32 cols/block, GRP=8,
//   W entries in registers, tagged-slot poll (8/thread), double-buffered vsh,
//   one barrier/step, fast tanh.
//   NEW: each lane's entry list is sorted by ((idx&31) - lane) & 31 at setup
//   (odd-even network, deterministic). At gather round k all 64 lanes of a
//   wave then read banks spread as (lane + delta_k) mod 32 -> ~conflict-free
//   (lane and lane+32 alias 2-way, which is free). Targets the measured
//   1512 conflict-cycles/block-step (SQ_LDS_BANK_CONFLICT = 3.96e8).
//   Reuse invariant (2-deep rotation, 1 barrier): producing v_{t+1} requires
//   having read all of v_t; a wave stages t+1 only after barrier t, which
//   implies every wave's MAC on parity (t-1) is complete.
// ---------------------------------------------------------------------------
#define RB   64    // blocks (1 per CU, trivially co-resident)
#define CPB  32    // columns per block
#define GRP  8     // lanes per column
#define CAP  288   // nnz capacity per column (mean 204.8, sigma 13.6 -> +6.1s)
#define KMAX (CAP / GRP)   // 36 register entries per lane

__device__ __forceinline__ float fast_tanh(float x) {
    const float ax = fabsf(x);
    const float e  = __expf(2.0f * ax);               // inf for big ax
    const float r  = __builtin_amdgcn_rcpf(e + 1.0f); // rcp(inf)=0 -> tanh=1
    const float t  = 1.0f - 2.0f * r;
    return copysignf(t, x);
}

__global__ __launch_bounds__(256, 1) void esn_recur(const float* __restrict__ W,
                                                    float* __restrict__ UO,
                                                    unsigned long long* vslots) {
    __shared__ unsigned long long ent[CPB][CAP];  // setup scratch only
    __shared__ int   cnts[CPB];
    __shared__ float vsh[2][N_OUT];               // double-buffered state

    const int tid = threadIdx.x;
    const int b   = blockIdx.x;
    const int c   = tid >> 3;              // column group 0..31
    const int l   = tid & 7;               // lane within group
    const int j   = b * CPB + c;           // global output column
    const int lw  = tid & 63;              // lane within wave (bank rotation)

    // ---------- build sparse column into LDS scratch (one-time) ----------
    int cnt = 0;
    for (int k = 0; k < N_OUT / GRP; k++) {
        const float w = W[(size_t)(l + GRP * k) * N_OUT + j];
        cnt += (w != 0.0f) ? 1 : 0;
    }
    int inc = cnt;
#pragma unroll
    for (int d = 1; d < GRP; d <<= 1) {
        int n = __shfl_up(inc, d, 64);
        if (l >= d) inc += n;
    }
    int pos = inc - cnt;
    if (l == GRP - 1) cnts[c] = inc;
    for (int k = 0; k < N_OUT / GRP; k++) {
        const int i = l + GRP * k;
        const float w = W[(size_t)i * N_OUT + j];
        if (w != 0.0f) {
            if (pos < CAP)
                ent[c][pos] = ((unsigned long long)(unsigned)i << 32) | __float_as_uint(w);
            pos++;
        }
    }
    __syncthreads();
    const int ccnt = min(cnts[c], CAP);

    // ---------- this lane's entries -> registers, padded to KMAX ----------
    float wreg[KMAX];
    int   ireg[KMAX];
#pragma unroll
    for (int k = 0; k < KMAX; k++) {
        const int p = l + k * GRP;
        if (p < ccnt) {
            const unsigned long long e = ent[c][p];
            wreg[k] = __uint_as_float((unsigned)e);
            ireg[k] = (int)(e >> 32);
        } else {
            wreg[k] = 0.f;   // pad: gathers vsh[0] (same-addr broadcast), w=0
            ireg[k] = 0;
        }
    }

    // ---------- bank-rotation sort (odd-even transposition, deterministic) --
    // key(e) = ((idx mod 32) - lane) mod 32; ascending. Round k then hits
    // bank ~ (lane + delta_k) mod 32 across the wave -> conflicts collapse.
#pragma unroll
    for (int pass = 0; pass < KMAX; ++pass) {
#pragma unroll
        for (int i = (pass & 1); i + 1 < KMAX; i += 2) {
            const int ka = ((ireg[i]     & 31) - lw) & 31;
            const int kb = ((ireg[i + 1] & 31) - lw) & 31;
            const bool sw = ka > kb;
            const int   ti = sw ? ireg[i] : ireg[i + 1];
            const int   bi = sw ? ireg[i + 1] : ireg[i];
            const float tw = sw ? wreg[i] : wreg[i + 1];
            const float bw = sw ? wreg[i + 1] : wreg[i];
            ireg[i] = bi; ireg[i + 1] = ti;
            wreg[i] = bw; wreg[i + 1] = tw;
        }
    }

    // ---------- sequential scan over T ----------
#pragma unroll 1
    for (int t = 0; t < T_STEPS; t++) {
        // prefetch this step's input projection (independent of v_t)
        float u = 0.f;
        if (l == 0) u = UO[(size_t)t * N_OUT + j];

        // ---- poll tagged slots for v_t (8 slots/thread, pending-only retries)
        unsigned long long* vin = vslots + (size_t)(t & 1) * N_OUT;
        float* dst = vsh[t & 1];
        unsigned long long uq[8];
#pragma unroll
        for (int q = 0; q < 8; q++)
            uq[q] = __hip_atomic_load(&vin[tid + q * 256], __ATOMIC_RELAXED,
                                      __HIP_MEMORY_SCOPE_AGENT);
        unsigned pend = 0xFFu;
#pragma unroll 1
        while (true) {
            unsigned np = 0;
#pragma unroll
            for (int q = 0; q < 8; q++) {
                if (pend & (1u << q)) {
                    if ((unsigned)(uq[q] >> 32) == (unsigned)t)
                        dst[tid + q * 256] = __uint_as_float((unsigned)uq[q]);
                    else
                        np |= (1u << q);
                }
            }
            pend = np;
            if (!pend) break;
#pragma unroll
            for (int q = 0; q < 8; q++)
                if (pend & (1u << q))
                    uq[q] = __hip_atomic_load(&vin[tid + q * 256], __ATOMIC_RELAXED,
                                              __HIP_MEMORY_SCOPE_AGENT);
        }
        __syncthreads();   // vsh[t&1] complete (single barrier per step)

        // ---- MAC from registers: 36 bank-scheduled LDS gathers, 4 accums ----
        const float* vcur = vsh[t & 1];
        float y0 = 0.f, y1 = 0.f, y2 = 0.f, y3 = 0.f;
#pragma unroll
        for (int k = 0; k < KMAX; k += 4) {
            y0 = fmaf(wreg[k + 0], vcur[ireg[k + 0]], y0);
            y1 = fmaf(wreg[k + 1], vcur[ireg[k + 1]], y1);
            y2 = fmaf(wreg[k + 2], vcur[ireg[k + 2]], y2);
            y3 = fmaf(wreg[k + 3], vcur[ireg[k + 3]], y3);
        }
        float y = (y0 + y1) + (y2 + y3);
#pragma unroll
        for (int d = GRP / 2; d >= 1; d >>= 1) y += __shfl_xor(y, d, 64);

        if (l == 0) {
            const float vnew = 0.5f * vcur[j] + 0.5f * fast_tanh(y + u);
            // slot store FIRST (inter-block critical path), then the output
            const unsigned long long slot =
                ((unsigned long long)(unsigned)(t + 1) << 32) | __float_as_uint(vnew);
            __hip_atomic_store(&vslots[(size_t)((t + 1) & 1) * N_OUT + j], slot,
                               __ATOMIC_RELAXED, __HIP_MEMORY_SCOPE_AGENT);
            UO[(size_t)t * N_OUT + j] = vnew;
        }
        // no trailing barrier: next step touches only vsh[(t+1)&1] (see invariant)
    }
}

// ---------------------------------------------------------------------------
extern "C" void kernel_launch(void* const* d_in, const int* in_sizes, int n_in,
                              void* d_out, int out_size, void* d_ws, size_t ws_size,
                              hipStream_t stream) {
    const float* x   = (const float*)d_in[0];   // [4096, 8192]
    const float* W   = (const float*)d_in[1];   // [2048, 2048]
    const float* Win = (const float*)d_in[2];   // [8192, 2048]
    float* out = (float*)d_out;                 // [4096, 2048]

    unsigned long long* vslots = (unsigned long long*)d_ws;  // 2 x N_OUT x 8B

    // zero tags+values: slot[0] becomes {tag=0, v=0} == the ESN zero state
    hipMemsetAsync(d_ws, 0, 2 * N_OUT * sizeof(unsigned long long), stream);

    dim3 ggrid(T_STEPS / 128, N_OUT / 128);
    gemm_xwin<<<ggrid, 256, 0, stream>>>(x, Win, out);

    esn_recur<<<RB, 256, 0, stream>>>(W, out, vslots);
}